// Round 21
// baseline (437.464 us; speedup 1.0000x reference)
//
#include <hip/hip_runtime.h>
#include <hip/hip_bf16.h>

#define IN_DIM 1024
#define HID 512
#define OUTD 256

typedef __attribute__((ext_vector_type(8))) short short8;
typedef __attribute__((ext_vector_type(4))) float f32x4;
typedef __attribute__((ext_vector_type(8))) unsigned short ushort8e;

// ---------------- helpers ----------------

__device__ inline unsigned short f2bf(float f) {
    union { float f; unsigned u; } v; v.f = f;
    unsigned r = (v.u + 0x7FFF + ((v.u >> 16) & 1)) >> 16;  // RNE
    return (unsigned short)r;
}

__device__ inline float bf2f(unsigned short u) {
    union { unsigned u; float f; } v; v.u = ((unsigned)u) << 16; return v.f;
}

__device__ inline void gload16(const void* g, void* l) {
    __builtin_amdgcn_global_load_lds(
        (const __attribute__((address_space(1))) void*)g,
        (__attribute__((address_space(3))) void*)l, 16, 0, 0);
}

// ---------------- degree / norm ----------------

__global__ void deg_kernel(const int* __restrict__ src, const int* __restrict__ dst,
                           int* __restrict__ dego, int* __restrict__ degi, int E) {
    int i = blockIdx.x * blockDim.x + threadIdx.x;
    if (i < E) {
        atomicAdd(&dego[src[i]], 1);
        atomicAdd(&degi[dst[i]], 1);
    }
}

__global__ void invsqrt_kernel(const int* __restrict__ dego, const int* __restrict__ degi,
                               float* __restrict__ iso, float* __restrict__ isi, int n) {
    int i = blockIdx.x * blockDim.x + threadIdx.x;
    if (i < n) {
        iso[i] = rsqrtf(fmaxf((float)dego[i], 1.0f));
        isi[i] = rsqrtf(fmaxf((float)degi[i], 1.0f));
    }
}

// ---------------- exclusive scan over N=65536 (256 blocks x 256) ----------------

__global__ __launch_bounds__(256) void scan_block(const int* __restrict__ deg,
                                                  int* __restrict__ excl,
                                                  int* __restrict__ partials) {
    __shared__ int tmp[256];
    int tid = threadIdx.x;
    int i = blockIdx.x * 256 + tid;
    int v = deg[i];
    tmp[tid] = v;
    __syncthreads();
    #pragma unroll
    for (int off = 1; off < 256; off <<= 1) {
        int t = (tid >= off) ? tmp[tid - off] : 0;
        __syncthreads();
        tmp[tid] += t;
        __syncthreads();
    }
    excl[i] = tmp[tid] - v;
    if (tid == 255) partials[blockIdx.x] = tmp[255];
}

__global__ __launch_bounds__(256) void scan_partials(int* __restrict__ partials) {
    __shared__ int tmp[256];
    int tid = threadIdx.x;
    int v = partials[tid];
    tmp[tid] = v;
    __syncthreads();
    #pragma unroll
    for (int off = 1; off < 256; off <<= 1) {
        int t = (tid >= off) ? tmp[tid - off] : 0;
        __syncthreads();
        tmp[tid] += t;
        __syncthreads();
    }
    partials[tid] = tmp[tid] - v;   // exclusive
}

__global__ __launch_bounds__(256) void scan_add(const int* __restrict__ excl,
                                                const int* __restrict__ partials,
                                                const int* __restrict__ deg,
                                                int* __restrict__ row_start,
                                                int* __restrict__ cursor, int n) {
    int i = blockIdx.x * 256 + threadIdx.x;
    int v = excl[i] + partials[blockIdx.x];
    row_start[i] = v;
    cursor[i] = v;
    if (i == n - 1) row_start[n] = v + deg[i];
}

__global__ void csr_fill(const int* __restrict__ src, const int* __restrict__ dst,
                         int* __restrict__ cursor, int* __restrict__ eidx, int E) {
    int e = blockIdx.x * blockDim.x + threadIdx.x;
    if (e < E) {
        int pos = atomicAdd(&cursor[dst[e]], 1);
        eidx[pos] = src[e];
    }
}

// ---------------- conversions ----------------

// y = bf16(x * rs[i>>logK]), grid-stride (R8-proven)
__global__ __launch_bounds__(256) void scale_cvt(
    const float* __restrict__ x, const float* __restrict__ rs,
    unsigned short* __restrict__ y, int logK, size_t total)
{
    const size_t stride = (size_t)gridDim.x * 256 * 8;
    for (size_t i = ((size_t)blockIdx.x * 256 + threadIdx.x) * 8; i < total; i += stride) {
        float s = rs[i >> logK];
        float4 a = *reinterpret_cast<const float4*>(x + i);
        float4 b = *reinterpret_cast<const float4*>(x + i + 4);
        short8 o;
        o[0] = (short)f2bf(a.x * s); o[1] = (short)f2bf(a.y * s);
        o[2] = (short)f2bf(a.z * s); o[3] = (short)f2bf(a.w * s);
        o[4] = (short)f2bf(b.x * s); o[5] = (short)f2bf(b.y * s);
        o[6] = (short)f2bf(b.z * s); o[7] = (short)f2bf(b.w * s);
        *reinterpret_cast<short8*>(y + i) = o;
    }
}

// 32x32 tiled transpose+cvt, coalesced both sides (R16-proven)
__global__ __launch_bounds__(256) void transpose_cvt_tiled(
    const float* __restrict__ W, unsigned short* __restrict__ Wt, int K, int N)
{
    __shared__ unsigned short tile[32][33];
    const int tx = threadIdx.x & 31;
    const int ty = threadIdx.x >> 5;
    const int n0 = blockIdx.x * 32;
    const int k0 = blockIdx.y * 32;

    #pragma unroll
    for (int j = 0; j < 4; ++j) {
        int k = ty + j * 8;
        tile[k][tx] = f2bf(W[(size_t)(k0 + k) * N + n0 + tx]);
    }
    __syncthreads();
    #pragma unroll
    for (int j = 0; j < 4; ++j) {
        int n = ty + j * 8;
        Wt[(size_t)(n0 + n) * K + k0 + tx] = tile[tx][n];
    }
}

// ---------------- GEMM1: R4-exact bf16 m97 loop + XCD swizzle ----------------
// C = A[M,K] @ Bt[Nc,K]^T, bf16 out. BK=32, single-buffered, 2 barriers,
// global_load_lds both operands (R4: measured ~100us HBM-bound at 528MB FETCH;
// swizzle cuts FETCH 3.7x -> the one proven-fast structure + the proven fix).

#define NXCD 8

__global__ __launch_bounds__(256) void gemm1_bf16(
    const unsigned short* __restrict__ A, const unsigned short* __restrict__ Bt,
    unsigned short* __restrict__ Cb, int M, int K, int Nc)
{
    __shared__ unsigned short As[128][32];   // 8 KB
    __shared__ unsigned short Bs[128][32];   // 8 KB

    const int tid  = threadIdx.x;
    const int lane = tid & 63;
    const int wave = tid >> 6;
    const int wr = wave >> 1, wc = wave & 1;
    const int lrow = lane & 15;
    const int lkg  = lane >> 4;

    // XCD swizzle: 4 column-siblings of one A-panel run on the same XCD
    const int per = gridDim.x / NXCD;
    const int newlin = (blockIdx.x % NXCD) * per + blockIdx.x / NXCD;
    const int ncb = Nc / 128;
    const int m0 = (newlin / ncb) * 128;
    const int n0 = (newlin % ncb) * 128;

    const int s0 = wave * 64 + lane;
    const int s1 = s0 + 256;
    const int r0 = s0 >> 2, q0 = (s0 & 3) ^ ((s0 >> 3) & 3);
    const int r1 = s1 >> 2, q1 = (s1 & 3) ^ ((s1 >> 3) & 3);

    char* AsB = (char*)&As[0][0];
    char* BsB = (char*)&Bs[0][0];
    void* ldsA0 = AsB + wave * 1024;
    void* ldsA1 = AsB + 4096 + wave * 1024;
    void* ldsB0 = BsB + wave * 1024;
    void* ldsB1 = BsB + 4096 + wave * 1024;

    const int rslot = (lkg ^ ((lrow >> 1) & 3)) * 8;

    f32x4 acc[4][4] = {};

    const int nk = K / 32;
    for (int kt = 0; kt < nk; ++kt) {
        const int k0 = kt * 32;
        gload16(A  + (size_t)(m0 + r0) * K + k0 + q0 * 8, ldsA0);
        gload16(A  + (size_t)(m0 + r1) * K + k0 + q1 * 8, ldsA1);
        gload16(Bt + (size_t)(n0 + r0) * K + k0 + q0 * 8, ldsB0);
        gload16(Bt + (size_t)(n0 + r1) * K + k0 + q1 * 8, ldsB1);
        __syncthreads();

        short8 af[4], bfr[4];
        #pragma unroll
        for (int mi = 0; mi < 4; ++mi)
            af[mi] = *reinterpret_cast<const short8*>(&As[wr * 64 + mi * 16 + lrow][rslot]);
        #pragma unroll
        for (int ni = 0; ni < 4; ++ni)
            bfr[ni] = *reinterpret_cast<const short8*>(&Bs[wc * 64 + ni * 16 + lrow][rslot]);

        #pragma unroll
        for (int mi = 0; mi < 4; ++mi)
            #pragma unroll
            for (int ni = 0; ni < 4; ++ni)
                acc[mi][ni] = __builtin_amdgcn_mfma_f32_16x16x32_bf16(
                    af[mi], bfr[ni], acc[mi][ni], 0, 0, 0);

        __syncthreads();
    }

    #pragma unroll
    for (int mi = 0; mi < 4; ++mi)
        #pragma unroll
        for (int ni = 0; ni < 4; ++ni)
            #pragma unroll
            for (int r = 0; r < 4; ++r)
                Cb[(size_t)(m0 + wr * 64 + mi * 16 + lkg * 4 + r) * Nc
                   + (n0 + wc * 64 + ni * 16 + lrow)] = f2bf(acc[mi][ni][r]);
}

// ---------------- GEMM2: bf16 A/B via gload_lds, BK=64 dbuf (R8 path) ----------------

#define TM 128
#define TN 128
#define TK 64

__global__ __launch_bounds__(256) void gemm2_bf16(
    const unsigned short* __restrict__ Ab, const unsigned short* __restrict__ Bt,
    unsigned short* __restrict__ Cb, int M, int K, int Nc)
{
    __shared__ unsigned short As[2][TM][TK];   // 2 x 16 KB
    __shared__ unsigned short Bs[2][TN][TK];   // 2 x 16 KB

    const int tid  = threadIdx.x;
    const int lane = tid & 63;
    const int wave = tid >> 6;
    const int wr = wave >> 1, wc = wave & 1;
    const int lrow = lane & 15;
    const int lkg  = lane >> 4;

    const int per = gridDim.x / NXCD;
    const int newlin = (blockIdx.x % NXCD) * per + blockIdx.x / NXCD;
    const int ncb = Nc / TN;
    const int m0 = (newlin / ncb) * TM;
    const int n0 = (newlin % ncb) * TN;

    int srow[4], sq[4];
    #pragma unroll
    for (int i = 0; i < 4; ++i) {
        int s = i * 256 + wave * 64 + lane;
        srow[i] = s >> 3;
        sq[i] = (s & 7) ^ ((s >> 3) & 7);
    }

    char* AsB = (char*)&As[0][0][0];
    char* BsB = (char*)&Bs[0][0][0];

    auto stageOp = [&](const unsigned short* G, int rc0, int kt, char* opBase, int buf) {
        const int k0 = kt * TK;
        #pragma unroll
        for (int i = 0; i < 4; ++i)
            gload16(G + (size_t)(rc0 + srow[i]) * K + k0 + sq[i] * 8,
                    opBase + buf * 16384 + (i * 256 + wave * 64) * 16);
    };

    f32x4 acc[4][4] = {};

    stageOp(Bt, n0, 0, BsB, 0);
    stageOp(Ab, m0, 0, AsB, 0);
    __syncthreads();

    const int nk = K / TK;
    for (int kt = 0; kt < nk; ++kt) {
        const int cur = kt & 1, nxt = cur ^ 1;

        if (kt + 1 < nk) {
            stageOp(Bt, n0, kt + 1, BsB, nxt);
            stageOp(Ab, m0, kt + 1, AsB, nxt);
        }

        #pragma unroll
        for (int ks = 0; ks < 2; ++ks) {
            short8 af[4], bfr[4];
            #pragma unroll
            for (int mi = 0; mi < 4; ++mi) {
                const int row = wr * 64 + mi * 16 + lrow;
                const int qp = (ks * 4 + lkg) ^ (lrow & 7);
                af[mi] = *reinterpret_cast<const short8*>(&As[cur][row][qp * 8]);
            }
            #pragma unroll
            for (int ni = 0; ni < 4; ++ni) {
                const int row = wc * 64 + ni * 16 + lrow;
                const int qp = (ks * 4 + lkg) ^ (lrow & 7);
                bfr[ni] = *reinterpret_cast<const short8*>(&Bs[cur][row][qp * 8]);
            }
            #pragma unroll
            for (int mi = 0; mi < 4; ++mi)
                #pragma unroll
                for (int ni = 0; ni < 4; ++ni)
                    acc[mi][ni] = __builtin_amdgcn_mfma_f32_16x16x32_bf16(
                        af[mi], bfr[ni], acc[mi][ni], 0, 0, 0);
        }

        __syncthreads();
    }

    #pragma unroll
    for (int mi = 0; mi < 4; ++mi)
        #pragma unroll
        for (int ni = 0; ni < 4; ++ni)
            #pragma unroll
            for (int r = 0; r < 4; ++r)
                Cb[(size_t)(m0 + wr * 64 + mi * 16 + lkg * 4 + r) * Nc
                   + (n0 + wc * 64 + ni * 16 + lrow)] = f2bf(acc[mi][ni][r]);
}

// ---------------- CSR gather-aggregate (bf16 X), fused epilogues ----------------
// Plain-sum gather (iso pre-applied in scale_cvt).
// ELU=1: out_bf = bf16(elu(sum*isi + b1) * iso[node]) ; else out_f = sum*isi + b2

template<int DIM, int LANES, bool ELU>
__global__ __launch_bounds__(256) void aggregate(
    const int* __restrict__ row_start, const int* __restrict__ eidx,
    const unsigned short* __restrict__ Xb, const float* __restrict__ isi,
    const float* __restrict__ iso, const float* __restrict__ bias,
    unsigned short* __restrict__ out_bf, float* __restrict__ out_f)
{
    constexpr int F = DIM / LANES;        // 8 both configs
    constexpr int NPB = 256 / LANES;      // nodes per block
    const int node = blockIdx.x * NPB + (threadIdx.x / LANES);
    const int lane = threadIdx.x % LANES;

    const int beg = row_start[node];
    const int end = row_start[node + 1];
    const unsigned short* base = Xb + lane * F;

    float acc[F] = {};
    int e = beg;
    for (; e + 3 < end; e += 4) {
        int i0 = eidx[e], i1 = eidx[e + 1], i2 = eidx[e + 2], i3 = eidx[e + 3];
        ushort8e v0 = *reinterpret_cast<const ushort8e*>(base + (size_t)i0 * DIM);
        ushort8e v1 = *reinterpret_cast<const ushort8e*>(base + (size_t)i1 * DIM);
        ushort8e v2 = *reinterpret_cast<const ushort8e*>(base + (size_t)i2 * DIM);
        ushort8e v3 = *reinterpret_cast<const ushort8e*>(base + (size_t)i3 * DIM);
        #pragma unroll
        for (int f = 0; f < F; ++f) {
            acc[f] += bf2f(v0[f]); acc[f] += bf2f(v1[f]);
            acc[f] += bf2f(v2[f]); acc[f] += bf2f(v3[f]);
        }
    }
    for (; e < end; ++e) {
        ushort8e v0 = *reinterpret_cast<const ushort8e*>(base + (size_t)eidx[e] * DIM);
        #pragma unroll
        for (int f = 0; f < F; ++f) acc[f] += bf2f(v0[f]);
    }

    const float si = isi[node];
    float bv[F];
    #pragma unroll
    for (int q = 0; q < F / 4; ++q)
        *reinterpret_cast<float4*>(&bv[q * 4]) =
            *reinterpret_cast<const float4*>(bias + lane * F + q * 4);

    if (ELU) {
        const float so = iso[node];
        short8 o;
        #pragma unroll
        for (int f = 0; f < F; ++f) {
            float v = acc[f] * si + bv[f];
            v = v > 0.f ? v : expm1f(v);
            o[f] = (short)f2bf(v * so);
        }
        *reinterpret_cast<short8*>(out_bf + (size_t)node * DIM + lane * F) = o;
    } else {
        #pragma unroll
        for (int q = 0; q < F / 4; ++q) {
            float4 v = make_float4(acc[q * 4 + 0] * si + bv[q * 4 + 0],
                                   acc[q * 4 + 1] * si + bv[q * 4 + 1],
                                   acc[q * 4 + 2] * si + bv[q * 4 + 2],
                                   acc[q * 4 + 3] * si + bv[q * 4 + 3]);
            *reinterpret_cast<float4*>(out_f + (size_t)node * DIM + lane * F + q * 4) = v;
        }
    }
}

// ---------------- launch ----------------

extern "C" void kernel_launch(void* const* d_in, const int* in_sizes, int n_in,
                              void* d_out, int out_size, void* d_ws, size_t ws_size,
                              hipStream_t stream) {
    const float* h  = (const float*)d_in[0];
    const float* W1 = (const float*)d_in[1];
    const float* b1 = (const float*)d_in[2];
    const float* W2 = (const float*)d_in[3];
    const float* b2 = (const float*)d_in[4];
    const int*   src = (const int*)d_in[5];
    const int*   dst = (const int*)d_in[6];

    const int N = in_sizes[0] / IN_DIM;   // 65536
    const int E = in_sizes[5];            // 524288
    float* out = (float*)d_out;

    // ---- workspace layout ----
    int* dego      = (int*)d_ws;                   // N
    int* degi      = dego + N;                     // N
    int* excl      = degi + N;                     // N
    int* partials  = excl + N;                     // 256
    int* row_start = partials + 256;               // N+1 (pad to N+64)
    int* cursor    = row_start + N + 64;           // N
    int* eidx      = cursor + N;                   // E
    float* iso     = (float*)(eidx + E);           // N
    float* isi     = iso + N;                      // N
    unsigned short* W1t = (unsigned short*)(isi + N);      // IN_DIM*HID
    unsigned short* W2t = W1t + (size_t)IN_DIM * HID;      // HID*OUTD
    unsigned short* hb  = W2t + (size_t)HID * OUTD;        // N*IN_DIM bf16 (134MB)
    unsigned short* X1b = hb + (size_t)N * IN_DIM;         // N*HID bf16 (67MB)
    unsigned short* X2b = X1b;                             // alias (X1 dead before gemm2 write)
    unsigned short* R2h = X1b + (size_t)N * HID;           // N*HID bf16 (67MB) — x1s

    hipMemsetAsync(dego, 0, sizeof(int) * (size_t)2 * N, stream);

    deg_kernel<<<(E + 255) / 256, 256, 0, stream>>>(src, dst, dego, degi, E);
    invsqrt_kernel<<<(N + 255) / 256, 256, 0, stream>>>(dego, degi, iso, isi, N);

    // CSR by dst
    scan_block<<<N / 256, 256, 0, stream>>>(degi, excl, partials);
    scan_partials<<<1, 256, 0, stream>>>(partials);
    scan_add<<<N / 256, 256, 0, stream>>>(excl, partials, degi, row_start, cursor, N);
    csr_fill<<<(E + 255) / 256, 256, 0, stream>>>(src, dst, cursor, eidx, E);

    // hb = bf16(iso ⊙ h); weights -> bf16 transposed (coalesced tiles)
    scale_cvt<<<2048, 256, 0, stream>>>(h, iso, hb, 10, (size_t)N * IN_DIM);
    {
        dim3 g1(HID / 32, IN_DIM / 32);
        transpose_cvt_tiled<<<g1, 256, 0, stream>>>(W1, W1t, IN_DIM, HID);
        dim3 g2(OUTD / 32, HID / 32);
        transpose_cvt_tiled<<<g2, 256, 0, stream>>>(W2, W2t, HID, OUTD);
    }

    // Layer 1: X1b = bf16(hb @ W1)  [R4-exact bf16 GEMM + XCD swizzle]
    gemm1_bf16<<<(N / 128) * (HID / 128), 256, 0, stream>>>(
        hb, W1t, X1b, N, IN_DIM, HID);
    aggregate<HID, 64, true><<<N / 4, 256, 0, stream>>>(
        row_start, eidx, X1b, isi, iso, b1, R2h, nullptr);

    // Layer 2: X2b = bf16(R2h @ W2) ; out = agg(X2b)*isi + b2  [32 lanes/node]
    gemm2_bf16<<<(N / TM) * (OUTD / TN), 256, 0, stream>>>(
        R2h, W2t, X2b, N, HID, OUTD);
    aggregate<OUTD, 32, false><<<N / 8, 256, 0, stream>>>(
        row_start, eidx, X2b, isi, iso, b2, nullptr, out);
}

// Round 22
// 391.709 us; speedup vs baseline: 1.1168x; 1.1168x over previous
//
#include <hip/hip_runtime.h>
#include <hip/hip_bf16.h>

#define IN_DIM 1024
#define HID 512
#define OUTD 256

typedef __attribute__((ext_vector_type(8))) short short8;
typedef __attribute__((ext_vector_type(4))) float f32x4;
typedef __attribute__((ext_vector_type(8))) unsigned short ushort8e;
typedef __attribute__((ext_vector_type(4))) unsigned int uint4e;

// ---------------- helpers ----------------

__device__ inline unsigned short f2bf(float f) {
    union { float f; unsigned u; } v; v.f = f;
    unsigned r = (v.u + 0x7FFF + ((v.u >> 16) & 1)) >> 16;  // RNE
    return (unsigned short)r;
}

__device__ inline float bf2f(unsigned short u) {
    union { unsigned u; float f; } v; v.u = ((unsigned)u) << 16; return v.f;
}

// two f32 -> packed bf16x2: round-half-up (add 0x8000) + byte-perm pack
__device__ inline unsigned pk2(float a, float b) {
    unsigned ua = __float_as_uint(a) + 0x8000u;
    unsigned ub = __float_as_uint(b) + 0x8000u;
#if __has_builtin(__builtin_amdgcn_perm)
    return __builtin_amdgcn_perm(ub, ua, 0x07060302u);   // lo = ua>>16, hi = ub>>16
#else
    return (ua >> 16) | (ub & 0xFFFF0000u);
#endif
}

__device__ inline void gload16(const void* g, void* l) {
    __builtin_amdgcn_global_load_lds(
        (const __attribute__((address_space(1))) void*)g,
        (__attribute__((address_space(3))) void*)l, 16, 0, 0);
}

// ---------------- degree / norm ----------------

__global__ void deg_kernel(const int* __restrict__ src, const int* __restrict__ dst,
                           int* __restrict__ dego, int* __restrict__ degi, int E) {
    int i = blockIdx.x * blockDim.x + threadIdx.x;
    if (i < E) {
        atomicAdd(&dego[src[i]], 1);
        atomicAdd(&degi[dst[i]], 1);
    }
}

__global__ void invsqrt_kernel(const int* __restrict__ dego, const int* __restrict__ degi,
                               float* __restrict__ iso, float* __restrict__ isi, int n) {
    int i = blockIdx.x * blockDim.x + threadIdx.x;
    if (i < n) {
        iso[i] = rsqrtf(fmaxf((float)dego[i], 1.0f));
        isi[i] = rsqrtf(fmaxf((float)degi[i], 1.0f));
    }
}

// ---------------- exclusive scan over N=65536 (256 blocks x 256) ----------------

__global__ __launch_bounds__(256) void scan_block(const int* __restrict__ deg,
                                                  int* __restrict__ excl,
                                                  int* __restrict__ partials) {
    __shared__ int tmp[256];
    int tid = threadIdx.x;
    int i = blockIdx.x * 256 + tid;
    int v = deg[i];
    tmp[tid] = v;
    __syncthreads();
    #pragma unroll
    for (int off = 1; off < 256; off <<= 1) {
        int t = (tid >= off) ? tmp[tid - off] : 0;
        __syncthreads();
        tmp[tid] += t;
        __syncthreads();
    }
    excl[i] = tmp[tid] - v;
    if (tid == 255) partials[blockIdx.x] = tmp[255];
}

__global__ __launch_bounds__(256) void scan_partials(int* __restrict__ partials) {
    __shared__ int tmp[256];
    int tid = threadIdx.x;
    int v = partials[tid];
    tmp[tid] = v;
    __syncthreads();
    #pragma unroll
    for (int off = 1; off < 256; off <<= 1) {
        int t = (tid >= off) ? tmp[tid - off] : 0;
        __syncthreads();
        tmp[tid] += t;
        __syncthreads();
    }
    partials[tid] = tmp[tid] - v;   // exclusive
}

__global__ __launch_bounds__(256) void scan_add(const int* __restrict__ excl,
                                                const int* __restrict__ partials,
                                                const int* __restrict__ deg,
                                                int* __restrict__ row_start,
                                                int* __restrict__ cursor, int n) {
    int i = blockIdx.x * 256 + threadIdx.x;
    int v = excl[i] + partials[blockIdx.x];
    row_start[i] = v;
    cursor[i] = v;
    if (i == n - 1) row_start[n] = v + deg[i];
}

__global__ void csr_fill(const int* __restrict__ src, const int* __restrict__ dst,
                         int* __restrict__ cursor, int* __restrict__ eidx, int E) {
    int e = blockIdx.x * blockDim.x + threadIdx.x;
    if (e < E) {
        int pos = atomicAdd(&cursor[dst[e]], 1);
        eidx[pos] = src[e];
    }
}

// ---------------- weight transpose+cvt: 32x32 LDS tile, coalesced both sides ----

__global__ __launch_bounds__(256) void transpose_cvt_tiled(
    const float* __restrict__ W, unsigned short* __restrict__ Wt, int K, int N)
{
    __shared__ unsigned short tile[32][33];
    const int tx = threadIdx.x & 31;
    const int ty = threadIdx.x >> 5;
    const int n0 = blockIdx.x * 32;
    const int k0 = blockIdx.y * 32;

    #pragma unroll
    for (int j = 0; j < 4; ++j) {
        int k = ty + j * 8;
        tile[k][tx] = f2bf(W[(size_t)(k0 + k) * N + n0 + tx]);
    }
    __syncthreads();
    #pragma unroll
    for (int j = 0; j < 4; ++j) {
        int n = ty + j * 8;
        Wt[(size_t)(n0 + n) * K + k0 + tx] = tile[tx][n];
    }
}

// ---------------- GEMM1 (R16-proven): A f32 via DMA, hole-padded LDS ----------
// C[M,HID] = bf16( A[M,IN_DIM] @ Bt[HID,IN_DIM]^T ); iso applied in aggregate.
// A tile: 128 rows x 9 slots of 16B (8 data + 1 hole) = 144B rows; pure
// global_load_lds staging; f32->bf16 cvt (pk2) in the MFMA phase.
// __launch_bounds__(256,4) caps regs for ~39% occupancy.

#define NXCD 8

__global__ __launch_bounds__(256, 4) void gemm1_f32lds(
    const float* __restrict__ A, const unsigned short* __restrict__ Bt,
    unsigned short* __restrict__ Cb, int M)
{
    constexpr int K  = IN_DIM;   // 1024
    constexpr int NC = HID;      // 512
    __shared__ float          As[128 * 36];  // 18 KB (144B rows, hole-padded)
    __shared__ unsigned short Bs[128][32];   // 8 KB

    const int tid  = threadIdx.x;
    const int lane = tid & 63;
    const int wave = tid >> 6;
    const int wr = wave >> 1, wc = wave & 1;
    const int lrow = lane & 15;
    const int lkg  = lane >> 4;

    const int per = gridDim.x / NXCD;
    const int newlin = (blockIdx.x % NXCD) * per + blockIdx.x / NXCD;
    const int ncb = NC / 128;                 // 4
    const int m0 = (newlin / ncb) * 128;
    const int n0 = (newlin % ncb) * 128;

    char* AsB = (char*)&As[0];
    char* BsB = (char*)&Bs[0][0];

    int arow[5], aq[5];
    #pragma unroll
    for (int i = 0; i < 5; ++i) {
        int s = i * 256 + wave * 64 + lane;
        int r = s / 9;
        int q = s - r * 9;
        arow[i] = r;
        aq[i] = (q == 8) ? 0 : q;
    }
    int brow[2], bq[2];
    #pragma unroll
    for (int i = 0; i < 2; ++i) {
        int s = i * 256 + wave * 64 + lane;
        brow[i] = s >> 2;
        bq[i] = (s & 3) ^ ((s >> 3) & 3);
    }

    const int rslotB = (lkg ^ ((lrow >> 1) & 3)) * 8;

    f32x4 acc[4][4] = {};

    for (int kt = 0; kt < K / 32; ++kt) {
        const int k0 = kt * 32;

        #pragma unroll
        for (int i = 0; i < 4; ++i)
            gload16(A + (size_t)(m0 + arow[i]) * K + k0 + aq[i] * 4,
                    AsB + (i * 256 + wave * 64) * 16);
        if (wave < 2)
            gload16(A + (size_t)(m0 + arow[4]) * K + k0 + aq[4] * 4,
                    AsB + (4 * 256 + wave * 64) * 16);
        #pragma unroll
        for (int i = 0; i < 2; ++i)
            gload16(Bt + (size_t)(n0 + brow[i]) * K + k0 + bq[i] * 8,
                    BsB + (i * 256 + wave * 64) * 16);

        __syncthreads();

        short8 af[4], bfr[4];
        #pragma unroll
        for (int mi = 0; mi < 4; ++mi) {
            const int row = wr * 64 + mi * 16 + lrow;
            const char* rb = AsB + row * 144 + lkg * 32;
            f32x4 a0 = *reinterpret_cast<const f32x4*>(rb);
            f32x4 a1 = *reinterpret_cast<const f32x4*>(rb + 16);
            uint4e u;
            u[0] = pk2(a0[0], a0[1]); u[1] = pk2(a0[2], a0[3]);
            u[2] = pk2(a1[0], a1[1]); u[3] = pk2(a1[2], a1[3]);
            af[mi] = *reinterpret_cast<short8*>(&u);
        }
        #pragma unroll
        for (int ni = 0; ni < 4; ++ni)
            bfr[ni] = *reinterpret_cast<const short8*>(&Bs[wc * 64 + ni * 16 + lrow][rslotB]);

        #pragma unroll
        for (int mi = 0; mi < 4; ++mi)
            #pragma unroll
            for (int ni = 0; ni < 4; ++ni)
                acc[mi][ni] = __builtin_amdgcn_mfma_f32_16x16x32_bf16(
                    af[mi], bfr[ni], acc[mi][ni], 0, 0, 0);

        __syncthreads();
    }

    #pragma unroll
    for (int mi = 0; mi < 4; ++mi)
        #pragma unroll
        for (int ni = 0; ni < 4; ++ni)
            #pragma unroll
            for (int r = 0; r < 4; ++r)
                Cb[(size_t)(m0 + wr * 64 + mi * 16 + lkg * 4 + r) * NC
                   + (n0 + wc * 64 + ni * 16 + lrow)] = f2bf(acc[mi][ni][r]);
}

// ---------------- GEMM2: bf16 A/B via gload_lds, BK=64 dbuf (R8 path) ----------------

#define TM 128
#define TN 128
#define TK 64

__global__ __launch_bounds__(256) void gemm2_bf16(
    const unsigned short* __restrict__ Ab, const unsigned short* __restrict__ Bt,
    unsigned short* __restrict__ Cb, int M, int K, int Nc)
{
    __shared__ unsigned short As[2][TM][TK];   // 2 x 16 KB
    __shared__ unsigned short Bs[2][TN][TK];   // 2 x 16 KB

    const int tid  = threadIdx.x;
    const int lane = tid & 63;
    const int wave = tid >> 6;
    const int wr = wave >> 1, wc = wave & 1;
    const int lrow = lane & 15;
    const int lkg  = lane >> 4;

    const int per = gridDim.x / NXCD;
    const int newlin = (blockIdx.x % NXCD) * per + blockIdx.x / NXCD;
    const int ncb = Nc / TN;
    const int m0 = (newlin / ncb) * TM;
    const int n0 = (newlin % ncb) * TN;

    int srow[4], sq[4];
    #pragma unroll
    for (int i = 0; i < 4; ++i) {
        int s = i * 256 + wave * 64 + lane;
        srow[i] = s >> 3;
        sq[i] = (s & 7) ^ ((s >> 3) & 7);
    }

    char* AsB = (char*)&As[0][0][0];
    char* BsB = (char*)&Bs[0][0][0];

    auto stageOp = [&](const unsigned short* G, int rc0, int kt, char* opBase, int buf) {
        const int k0 = kt * TK;
        #pragma unroll
        for (int i = 0; i < 4; ++i)
            gload16(G + (size_t)(rc0 + srow[i]) * K + k0 + sq[i] * 8,
                    opBase + buf * 16384 + (i * 256 + wave * 64) * 16);
    };

    f32x4 acc[4][4] = {};

    stageOp(Bt, n0, 0, BsB, 0);
    stageOp(Ab, m0, 0, AsB, 0);
    __syncthreads();

    const int nk = K / TK;
    for (int kt = 0; kt < nk; ++kt) {
        const int cur = kt & 1, nxt = cur ^ 1;

        if (kt + 1 < nk) {
            stageOp(Bt, n0, kt + 1, BsB, nxt);
            stageOp(Ab, m0, kt + 1, AsB, nxt);
        }

        #pragma unroll
        for (int ks = 0; ks < 2; ++ks) {
            short8 af[4], bfr[4];
            #pragma unroll
            for (int mi = 0; mi < 4; ++mi) {
                const int row = wr * 64 + mi * 16 + lrow;
                const int qp = (ks * 4 + lkg) ^ (lrow & 7);
                af[mi] = *reinterpret_cast<const short8*>(&As[cur][row][qp * 8]);
            }
            #pragma unroll
            for (int ni = 0; ni < 4; ++ni) {
                const int row = wc * 64 + ni * 16 + lrow;
                const int qp = (ks * 4 + lkg) ^ (lrow & 7);
                bfr[ni] = *reinterpret_cast<const short8*>(&Bs[cur][row][qp * 8]);
            }
            #pragma unroll
            for (int mi = 0; mi < 4; ++mi)
                #pragma unroll
                for (int ni = 0; ni < 4; ++ni)
                    acc[mi][ni] = __builtin_amdgcn_mfma_f32_16x16x32_bf16(
                        af[mi], bfr[ni], acc[mi][ni], 0, 0, 0);
        }

        __syncthreads();
    }

    #pragma unroll
    for (int mi = 0; mi < 4; ++mi)
        #pragma unroll
        for (int ni = 0; ni < 4; ++ni)
            #pragma unroll
            for (int r = 0; r < 4; ++r)
                Cb[(size_t)(m0 + wr * 64 + mi * 16 + lkg * 4 + r) * Nc
                   + (n0 + wc * 64 + ni * 16 + lrow)] = f2bf(acc[mi][ni][r]);
}

// ---------------- CSR gather-aggregate (bf16 X), fused epilogues ----------------
// LANES lanes per node (64 for DIM=512, 32 for DIM=256 -> 16B loads both).
// LAYER1: acc = sum iso[src]*X[src]; out_bf = bf16(elu(acc*isi + b1) * iso[node])
// else:   acc = sum X[src];          out_f  = acc*isi + b2

template<int DIM, int LANES, bool LAYER1>
__global__ __launch_bounds__(256) void aggregate(
    const int* __restrict__ row_start, const int* __restrict__ eidx,
    const unsigned short* __restrict__ Xb, const float* __restrict__ isi,
    const float* __restrict__ iso, const float* __restrict__ bias,
    unsigned short* __restrict__ out_bf, float* __restrict__ out_f)
{
    constexpr int F = DIM / LANES;        // 8 both configs
    constexpr int NPB = 256 / LANES;      // nodes per block
    const int node = blockIdx.x * NPB + (threadIdx.x / LANES);
    const int lane = threadIdx.x % LANES;

    const int beg = row_start[node];
    const int end = row_start[node + 1];
    const unsigned short* base = Xb + lane * F;

    float acc[F] = {};
    int e = beg;
    for (; e + 3 < end; e += 4) {
        int i0 = eidx[e], i1 = eidx[e + 1], i2 = eidx[e + 2], i3 = eidx[e + 3];
        float s0 = 1.f, s1 = 1.f, s2 = 1.f, s3 = 1.f;
        if (LAYER1) { s0 = iso[i0]; s1 = iso[i1]; s2 = iso[i2]; s3 = iso[i3]; }
        ushort8e v0 = *reinterpret_cast<const ushort8e*>(base + (size_t)i0 * DIM);
        ushort8e v1 = *reinterpret_cast<const ushort8e*>(base + (size_t)i1 * DIM);
        ushort8e v2 = *reinterpret_cast<const ushort8e*>(base + (size_t)i2 * DIM);
        ushort8e v3 = *reinterpret_cast<const ushort8e*>(base + (size_t)i3 * DIM);
        #pragma unroll
        for (int f = 0; f < F; ++f) {
            if (LAYER1) {
                acc[f] = fmaf(s0, bf2f(v0[f]), acc[f]);
                acc[f] = fmaf(s1, bf2f(v1[f]), acc[f]);
                acc[f] = fmaf(s2, bf2f(v2[f]), acc[f]);
                acc[f] = fmaf(s3, bf2f(v3[f]), acc[f]);
            } else {
                acc[f] += bf2f(v0[f]); acc[f] += bf2f(v1[f]);
                acc[f] += bf2f(v2[f]); acc[f] += bf2f(v3[f]);
            }
        }
    }
    for (; e < end; ++e) {
        int i0 = eidx[e];
        float s0 = LAYER1 ? iso[i0] : 1.f;
        ushort8e v0 = *reinterpret_cast<const ushort8e*>(base + (size_t)i0 * DIM);
        #pragma unroll
        for (int f = 0; f < F; ++f)
            acc[f] = LAYER1 ? fmaf(s0, bf2f(v0[f]), acc[f]) : acc[f] + bf2f(v0[f]);
    }

    const float si = isi[node];
    float bv[F];
    #pragma unroll
    for (int q = 0; q < F / 4; ++q)
        *reinterpret_cast<float4*>(&bv[q * 4]) =
            *reinterpret_cast<const float4*>(bias + lane * F + q * 4);

    if (LAYER1) {
        const float so = iso[node];
        short8 o;
        #pragma unroll
        for (int f = 0; f < F; ++f) {
            float v = acc[f] * si + bv[f];
            v = v > 0.f ? v : expm1f(v);
            o[f] = (short)f2bf(v * so);
        }
        *reinterpret_cast<short8*>(out_bf + (size_t)node * DIM + lane * F) = o;
    } else {
        #pragma unroll
        for (int q = 0; q < F / 4; ++q) {
            float4 v = make_float4(acc[q * 4 + 0] * si + bv[q * 4 + 0],
                                   acc[q * 4 + 1] * si + bv[q * 4 + 1],
                                   acc[q * 4 + 2] * si + bv[q * 4 + 2],
                                   acc[q * 4 + 3] * si + bv[q * 4 + 3]);
            *reinterpret_cast<float4*>(out_f + (size_t)node * DIM + lane * F + q * 4) = v;
        }
    }
}

// ---------------- launch ----------------

extern "C" void kernel_launch(void* const* d_in, const int* in_sizes, int n_in,
                              void* d_out, int out_size, void* d_ws, size_t ws_size,
                              hipStream_t stream) {
    const float* h  = (const float*)d_in[0];
    const float* W1 = (const float*)d_in[1];
    const float* b1 = (const float*)d_in[2];
    const float* W2 = (const float*)d_in[3];
    const float* b2 = (const float*)d_in[4];
    const int*   src = (const int*)d_in[5];
    const int*   dst = (const int*)d_in[6];

    const int N = in_sizes[0] / IN_DIM;   // 65536
    const int E = in_sizes[5];            // 524288
    float* out = (float*)d_out;

    // ---- workspace layout ----
    int* dego      = (int*)d_ws;                   // N
    int* degi      = dego + N;                     // N
    int* excl      = degi + N;                     // N
    int* partials  = excl + N;                     // 256
    int* row_start = partials + 256;               // N+1 (pad to N+64)
    int* cursor    = row_start + N + 64;           // N
    int* eidx      = cursor + N;                   // E
    float* iso     = (float*)(eidx + E);           // N
    float* isi     = iso + N;                      // N
    unsigned short* W1t = (unsigned short*)(isi + N);      // IN_DIM*HID
    unsigned short* W2t = W1t + (size_t)IN_DIM * HID;      // HID*OUTD
    unsigned short* X1b = W2t + (size_t)HID * OUTD;        // N*HID bf16 (67MB)
    unsigned short* X2b = X1b;                             // alias (X1 dead before gemm2 write)
    unsigned short* R2h = X1b + (size_t)N * HID;           // N*HID bf16 (67MB) — x1s

    hipMemsetAsync(dego, 0, sizeof(int) * (size_t)2 * N, stream);

    deg_kernel<<<(E + 255) / 256, 256, 0, stream>>>(src, dst, dego, degi, E);
    invsqrt_kernel<<<(N + 255) / 256, 256, 0, stream>>>(dego, degi, iso, isi, N);

    // CSR by dst
    scan_block<<<N / 256, 256, 0, stream>>>(degi, excl, partials);
    scan_partials<<<1, 256, 0, stream>>>(partials);
    scan_add<<<N / 256, 256, 0, stream>>>(excl, partials, degi, row_start, cursor, N);
    csr_fill<<<(E + 255) / 256, 256, 0, stream>>>(src, dst, cursor, eidx, E);

    // weights -> bf16 transposed (tiled, coalesced)
    {
        dim3 g1(HID / 32, IN_DIM / 32);
        transpose_cvt_tiled<<<g1, 256, 0, stream>>>(W1, W1t, IN_DIM, HID);
        dim3 g2(OUTD / 32, HID / 32);
        transpose_cvt_tiled<<<g2, 256, 0, stream>>>(W2, W2t, HID, OUTD);
    }

    // Layer 1: X1b = bf16(h @ W1) [R16-proven fused f32-A]; aggregate applies iso[src]
    gemm1_f32lds<<<(N / 128) * (HID / 128), 256, 0, stream>>>(h, W1t, X1b, N);
    aggregate<HID, 64, true><<<N / 4, 256, 0, stream>>>(
        row_start, eidx, X1b, isi, iso, b1, R2h, nullptr);

    // Layer 2: X2b = bf16(R2h @ W2) ; out = agg(X2b)*isi + b2  [32 lanes/node]
    gemm2_bf16<<<(N / TM) * (OUTD / TN), 256, 0, stream>>>(
        R2h, W2t, X2b, N, HID, OUTD);
    aggregate<OUTD, 32, false><<<N / 8, 256, 0, stream>>>(
        row_start, eidx, X2b, isi, iso, b2, nullptr, out);
}

// Round 23
// 390.080 us; speedup vs baseline: 1.1215x; 1.0042x over previous
//
#include <hip/hip_runtime.h>
#include <hip/hip_bf16.h>

#define IN_DIM 1024
#define HID 512
#define OUTD 256

typedef __attribute__((ext_vector_type(8))) short short8;
typedef __attribute__((ext_vector_type(4))) float f32x4;
typedef __attribute__((ext_vector_type(8))) unsigned short ushort8e;
typedef __attribute__((ext_vector_type(4))) unsigned int uint4e;

// ---------------- helpers ----------------

__device__ inline unsigned short f2bf(float f) {
    union { float f; unsigned u; } v; v.f = f;
    unsigned r = (v.u + 0x7FFF + ((v.u >> 16) & 1)) >> 16;  // RNE
    return (unsigned short)r;
}

__device__ inline float bf2f(unsigned short u) {
    union { unsigned u; float f; } v; v.u = ((unsigned)u) << 16; return v.f;
}

// two f32 -> packed bf16x2: round-half-up (add 0x8000) + byte-perm pack
__device__ inline unsigned pk2(float a, float b) {
    unsigned ua = __float_as_uint(a) + 0x8000u;
    unsigned ub = __float_as_uint(b) + 0x8000u;
#if __has_builtin(__builtin_amdgcn_perm)
    return __builtin_amdgcn_perm(ub, ua, 0x07060302u);   // lo = ua>>16, hi = ub>>16
#else
    return (ua >> 16) | (ub & 0xFFFF0000u);
#endif
}

__device__ inline void gload16(const void* g, void* l) {
    __builtin_amdgcn_global_load_lds(
        (const __attribute__((address_space(1))) void*)g,
        (__attribute__((address_space(3))) void*)l, 16, 0, 0);
}

// ---------------- degree ----------------

__global__ void deg_kernel(const int* __restrict__ src, const int* __restrict__ dst,
                           int* __restrict__ dego, int* __restrict__ degi, int E) {
    int i = blockIdx.x * blockDim.x + threadIdx.x;
    if (i < E) {
        atomicAdd(&dego[src[i]], 1);
        atomicAdd(&degi[dst[i]], 1);
    }
}

// ---------------- exclusive scan over N=65536 (256 blocks x 256) ----------------

__global__ __launch_bounds__(256) void scan_block(const int* __restrict__ deg,
                                                  int* __restrict__ excl,
                                                  int* __restrict__ partials) {
    __shared__ int tmp[256];
    int tid = threadIdx.x;
    int i = blockIdx.x * 256 + tid;
    int v = deg[i];
    tmp[tid] = v;
    __syncthreads();
    #pragma unroll
    for (int off = 1; off < 256; off <<= 1) {
        int t = (tid >= off) ? tmp[tid - off] : 0;
        __syncthreads();
        tmp[tid] += t;
        __syncthreads();
    }
    excl[i] = tmp[tid] - v;
    if (tid == 255) partials[blockIdx.x] = tmp[255];
}

__global__ __launch_bounds__(256) void scan_partials(int* __restrict__ partials) {
    __shared__ int tmp[256];
    int tid = threadIdx.x;
    int v = partials[tid];
    tmp[tid] = v;
    __syncthreads();
    #pragma unroll
    for (int off = 1; off < 256; off <<= 1) {
        int t = (tid >= off) ? tmp[tid - off] : 0;
        __syncthreads();
        tmp[tid] += t;
        __syncthreads();
    }
    partials[tid] = tmp[tid] - v;   // exclusive
}

// scan_add + fused invsqrt: one pass writes row_start/cursor AND iso/isi
__global__ __launch_bounds__(256) void scan_add_norm(
    const int* __restrict__ excl, const int* __restrict__ partials,
    const int* __restrict__ degi, const int* __restrict__ dego,
    int* __restrict__ row_start, int* __restrict__ cursor,
    float* __restrict__ iso, float* __restrict__ isi, int n)
{
    int i = blockIdx.x * 256 + threadIdx.x;
    int v = excl[i] + partials[blockIdx.x];
    row_start[i] = v;
    cursor[i] = v;
    if (i == n - 1) row_start[n] = v + degi[i];
    iso[i] = rsqrtf(fmaxf((float)dego[i], 1.0f));
    isi[i] = rsqrtf(fmaxf((float)degi[i], 1.0f));
}

__global__ void csr_fill(const int* __restrict__ src, const int* __restrict__ dst,
                         int* __restrict__ cursor, int* __restrict__ eidx, int E) {
    int e = blockIdx.x * blockDim.x + threadIdx.x;
    if (e < E) {
        int pos = atomicAdd(&cursor[dst[e]], 1);
        eidx[pos] = src[e];
    }
}

// ---------------- weight transpose+cvt: 32x32 LDS tile, coalesced both sides ----

__global__ __launch_bounds__(256) void transpose_cvt_tiled(
    const float* __restrict__ W, unsigned short* __restrict__ Wt, int K, int N)
{
    __shared__ unsigned short tile[32][33];
    const int tx = threadIdx.x & 31;
    const int ty = threadIdx.x >> 5;
    const int n0 = blockIdx.x * 32;
    const int k0 = blockIdx.y * 32;

    #pragma unroll
    for (int j = 0; j < 4; ++j) {
        int k = ty + j * 8;
        tile[k][tx] = f2bf(W[(size_t)(k0 + k) * N + n0 + tx]);
    }
    __syncthreads();
    #pragma unroll
    for (int j = 0; j < 4; ++j) {
        int n = ty + j * 8;
        Wt[(size_t)(n0 + n) * K + k0 + tx] = tile[tx][n];
    }
}

// ---------------- GEMM1 (R16-proven): A f32 via DMA, hole-padded LDS ----------
// C[M,HID] = bf16( A[M,IN_DIM] @ Bt[HID,IN_DIM]^T ); iso applied in aggregate.
// A tile: 128 rows x 9 slots of 16B (8 data + 1 hole) = 144B rows; pure
// global_load_lds staging; f32->bf16 cvt (pk2) in the MFMA phase.
// __launch_bounds__(256,4) caps regs for ~39% occupancy.

#define NXCD 8

__global__ __launch_bounds__(256, 4) void gemm1_f32lds(
    const float* __restrict__ A, const unsigned short* __restrict__ Bt,
    unsigned short* __restrict__ Cb, int M)
{
    constexpr int K  = IN_DIM;   // 1024
    constexpr int NC = HID;      // 512
    __shared__ float          As[128 * 36];  // 18 KB (144B rows, hole-padded)
    __shared__ unsigned short Bs[128][32];   // 8 KB

    const int tid  = threadIdx.x;
    const int lane = tid & 63;
    const int wave = tid >> 6;
    const int wr = wave >> 1, wc = wave & 1;
    const int lrow = lane & 15;
    const int lkg  = lane >> 4;

    const int per = gridDim.x / NXCD;
    const int newlin = (blockIdx.x % NXCD) * per + blockIdx.x / NXCD;
    const int ncb = NC / 128;                 // 4
    const int m0 = (newlin / ncb) * 128;
    const int n0 = (newlin % ncb) * 128;

    char* AsB = (char*)&As[0];
    char* BsB = (char*)&Bs[0][0];

    int arow[5], aq[5];
    #pragma unroll
    for (int i = 0; i < 5; ++i) {
        int s = i * 256 + wave * 64 + lane;
        int r = s / 9;
        int q = s - r * 9;
        arow[i] = r;
        aq[i] = (q == 8) ? 0 : q;
    }
    int brow[2], bq[2];
    #pragma unroll
    for (int i = 0; i < 2; ++i) {
        int s = i * 256 + wave * 64 + lane;
        brow[i] = s >> 2;
        bq[i] = (s & 3) ^ ((s >> 3) & 3);
    }

    const int rslotB = (lkg ^ ((lrow >> 1) & 3)) * 8;

    f32x4 acc[4][4] = {};

    for (int kt = 0; kt < K / 32; ++kt) {
        const int k0 = kt * 32;

        #pragma unroll
        for (int i = 0; i < 4; ++i)
            gload16(A + (size_t)(m0 + arow[i]) * K + k0 + aq[i] * 4,
                    AsB + (i * 256 + wave * 64) * 16);
        if (wave < 2)
            gload16(A + (size_t)(m0 + arow[4]) * K + k0 + aq[4] * 4,
                    AsB + (4 * 256 + wave * 64) * 16);
        #pragma unroll
        for (int i = 0; i < 2; ++i)
            gload16(Bt + (size_t)(n0 + brow[i]) * K + k0 + bq[i] * 8,
                    BsB + (i * 256 + wave * 64) * 16);

        __syncthreads();

        short8 af[4], bfr[4];
        #pragma unroll
        for (int mi = 0; mi < 4; ++mi) {
            const int row = wr * 64 + mi * 16 + lrow;
            const char* rb = AsB + row * 144 + lkg * 32;
            f32x4 a0 = *reinterpret_cast<const f32x4*>(rb);
            f32x4 a1 = *reinterpret_cast<const f32x4*>(rb + 16);
            uint4e u;
            u[0] = pk2(a0[0], a0[1]); u[1] = pk2(a0[2], a0[3]);
            u[2] = pk2(a1[0], a1[1]); u[3] = pk2(a1[2], a1[3]);
            af[mi] = *reinterpret_cast<short8*>(&u);
        }
        #pragma unroll
        for (int ni = 0; ni < 4; ++ni)
            bfr[ni] = *reinterpret_cast<const short8*>(&Bs[wc * 64 + ni * 16 + lrow][rslotB]);

        #pragma unroll
        for (int mi = 0; mi < 4; ++mi)
            #pragma unroll
            for (int ni = 0; ni < 4; ++ni)
                acc[mi][ni] = __builtin_amdgcn_mfma_f32_16x16x32_bf16(
                    af[mi], bfr[ni], acc[mi][ni], 0, 0, 0);

        __syncthreads();
    }

    #pragma unroll
    for (int mi = 0; mi < 4; ++mi)
        #pragma unroll
        for (int ni = 0; ni < 4; ++ni)
            #pragma unroll
            for (int r = 0; r < 4; ++r)
                Cb[(size_t)(m0 + wr * 64 + mi * 16 + lkg * 4 + r) * NC
                   + (n0 + wc * 64 + ni * 16 + lrow)] = f2bf(acc[mi][ni][r]);
}

// ---------------- GEMM2: bf16 A/B via gload_lds, BK=64 dbuf (R8 path) ----------------

#define TM 128
#define TN 128
#define TK 64

__global__ __launch_bounds__(256) void gemm2_bf16(
    const unsigned short* __restrict__ Ab, const unsigned short* __restrict__ Bt,
    unsigned short* __restrict__ Cb, int M, int K, int Nc)
{
    __shared__ unsigned short As[2][TM][TK];   // 2 x 16 KB
    __shared__ unsigned short Bs[2][TN][TK];   // 2 x 16 KB

    const int tid  = threadIdx.x;
    const int lane = tid & 63;
    const int wave = tid >> 6;
    const int wr = wave >> 1, wc = wave & 1;
    const int lrow = lane & 15;
    const int lkg  = lane >> 4;

    const int per = gridDim.x / NXCD;
    const int newlin = (blockIdx.x % NXCD) * per + blockIdx.x / NXCD;
    const int ncb = Nc / TN;
    const int m0 = (newlin / ncb) * TM;
    const int n0 = (newlin % ncb) * TN;

    int srow[4], sq[4];
    #pragma unroll
    for (int i = 0; i < 4; ++i) {
        int s = i * 256 + wave * 64 + lane;
        srow[i] = s >> 3;
        sq[i] = (s & 7) ^ ((s >> 3) & 7);
    }

    char* AsB = (char*)&As[0][0][0];
    char* BsB = (char*)&Bs[0][0][0];

    auto stageOp = [&](const unsigned short* G, int rc0, int kt, char* opBase, int buf) {
        const int k0 = kt * TK;
        #pragma unroll
        for (int i = 0; i < 4; ++i)
            gload16(G + (size_t)(rc0 + srow[i]) * K + k0 + sq[i] * 8,
                    opBase + buf * 16384 + (i * 256 + wave * 64) * 16);
    };

    f32x4 acc[4][4] = {};

    stageOp(Bt, n0, 0, BsB, 0);
    stageOp(Ab, m0, 0, AsB, 0);
    __syncthreads();

    const int nk = K / TK;
    for (int kt = 0; kt < nk; ++kt) {
        const int cur = kt & 1, nxt = cur ^ 1;

        if (kt + 1 < nk) {
            stageOp(Bt, n0, kt + 1, BsB, nxt);
            stageOp(Ab, m0, kt + 1, AsB, nxt);
        }

        #pragma unroll
        for (int ks = 0; ks < 2; ++ks) {
            short8 af[4], bfr[4];
            #pragma unroll
            for (int mi = 0; mi < 4; ++mi) {
                const int row = wr * 64 + mi * 16 + lrow;
                const int qp = (ks * 4 + lkg) ^ (lrow & 7);
                af[mi] = *reinterpret_cast<const short8*>(&As[cur][row][qp * 8]);
            }
            #pragma unroll
            for (int ni = 0; ni < 4; ++ni) {
                const int row = wc * 64 + ni * 16 + lrow;
                const int qp = (ks * 4 + lkg) ^ (lrow & 7);
                bfr[ni] = *reinterpret_cast<const short8*>(&Bs[cur][row][qp * 8]);
            }
            #pragma unroll
            for (int mi = 0; mi < 4; ++mi)
                #pragma unroll
                for (int ni = 0; ni < 4; ++ni)
                    acc[mi][ni] = __builtin_amdgcn_mfma_f32_16x16x32_bf16(
                        af[mi], bfr[ni], acc[mi][ni], 0, 0, 0);
        }

        __syncthreads();
    }

    #pragma unroll
    for (int mi = 0; mi < 4; ++mi)
        #pragma unroll
        for (int ni = 0; ni < 4; ++ni)
            #pragma unroll
            for (int r = 0; r < 4; ++r)
                Cb[(size_t)(m0 + wr * 64 + mi * 16 + lkg * 4 + r) * Nc
                   + (n0 + wc * 64 + ni * 16 + lrow)] = f2bf(acc[mi][ni][r]);
}

// ---------------- CSR gather-aggregate (bf16 X), fused epilogues ----------------
// LANES lanes per node (64 for DIM=512, 32 for DIM=256 -> 16B loads both).
// LAYER1: acc = sum iso[src]*X[src]; out_bf = bf16(elu(acc*isi + b1) * iso[node])
// else:   acc = sum X[src];          out_f  = acc*isi + b2

template<int DIM, int LANES, bool LAYER1>
__global__ __launch_bounds__(256) void aggregate(
    const int* __restrict__ row_start, const int* __restrict__ eidx,
    const unsigned short* __restrict__ Xb, const float* __restrict__ isi,
    const float* __restrict__ iso, const float* __restrict__ bias,
    unsigned short* __restrict__ out_bf, float* __restrict__ out_f)
{
    constexpr int F = DIM / LANES;        // 8 both configs
    constexpr int NPB = 256 / LANES;      // nodes per block
    const int node = blockIdx.x * NPB + (threadIdx.x / LANES);
    const int lane = threadIdx.x % LANES;

    const int beg = row_start[node];
    const int end = row_start[node + 1];
    const unsigned short* base = Xb + lane * F;

    float acc[F] = {};
    int e = beg;
    for (; e + 3 < end; e += 4) {
        int i0 = eidx[e], i1 = eidx[e + 1], i2 = eidx[e + 2], i3 = eidx[e + 3];
        float s0 = 1.f, s1 = 1.f, s2 = 1.f, s3 = 1.f;
        if (LAYER1) { s0 = iso[i0]; s1 = iso[i1]; s2 = iso[i2]; s3 = iso[i3]; }
        ushort8e v0 = *reinterpret_cast<const ushort8e*>(base + (size_t)i0 * DIM);
        ushort8e v1 = *reinterpret_cast<const ushort8e*>(base + (size_t)i1 * DIM);
        ushort8e v2 = *reinterpret_cast<const ushort8e*>(base + (size_t)i2 * DIM);
        ushort8e v3 = *reinterpret_cast<const ushort8e*>(base + (size_t)i3 * DIM);
        #pragma unroll
        for (int f = 0; f < F; ++f) {
            if (LAYER1) {
                acc[f] = fmaf(s0, bf2f(v0[f]), acc[f]);
                acc[f] = fmaf(s1, bf2f(v1[f]), acc[f]);
                acc[f] = fmaf(s2, bf2f(v2[f]), acc[f]);
                acc[f] = fmaf(s3, bf2f(v3[f]), acc[f]);
            } else {
                acc[f] += bf2f(v0[f]); acc[f] += bf2f(v1[f]);
                acc[f] += bf2f(v2[f]); acc[f] += bf2f(v3[f]);
            }
        }
    }
    for (; e < end; ++e) {
        int i0 = eidx[e];
        float s0 = LAYER1 ? iso[i0] : 1.f;
        ushort8e v0 = *reinterpret_cast<const ushort8e*>(base + (size_t)i0 * DIM);
        #pragma unroll
        for (int f = 0; f < F; ++f)
            acc[f] = LAYER1 ? fmaf(s0, bf2f(v0[f]), acc[f]) : acc[f] + bf2f(v0[f]);
    }

    const float si = isi[node];
    float bv[F];
    #pragma unroll
    for (int q = 0; q < F / 4; ++q)
        *reinterpret_cast<float4*>(&bv[q * 4]) =
            *reinterpret_cast<const float4*>(bias + lane * F + q * 4);

    if (LAYER1) {
        const float so = iso[node];
        short8 o;
        #pragma unroll
        for (int f = 0; f < F; ++f) {
            float v = acc[f] * si + bv[f];
            v = v > 0.f ? v : expm1f(v);
            o[f] = (short)f2bf(v * so);
        }
        *reinterpret_cast<short8*>(out_bf + (size_t)node * DIM + lane * F) = o;
    } else {
        #pragma unroll
        for (int q = 0; q < F / 4; ++q) {
            float4 v = make_float4(acc[q * 4 + 0] * si + bv[q * 4 + 0],
                                   acc[q * 4 + 1] * si + bv[q * 4 + 1],
                                   acc[q * 4 + 2] * si + bv[q * 4 + 2],
                                   acc[q * 4 + 3] * si + bv[q * 4 + 3]);
            *reinterpret_cast<float4*>(out_f + (size_t)node * DIM + lane * F + q * 4) = v;
        }
    }
}

// ---------------- launch ----------------

extern "C" void kernel_launch(void* const* d_in, const int* in_sizes, int n_in,
                              void* d_out, int out_size, void* d_ws, size_t ws_size,
                              hipStream_t stream) {
    const float* h  = (const float*)d_in[0];
    const float* W1 = (const float*)d_in[1];
    const float* b1 = (const float*)d_in[2];
    const float* W2 = (const float*)d_in[3];
    const float* b2 = (const float*)d_in[4];
    const int*   src = (const int*)d_in[5];
    const int*   dst = (const int*)d_in[6];

    const int N = in_sizes[0] / IN_DIM;   // 65536
    const int E = in_sizes[5];            // 524288
    float* out = (float*)d_out;

    // ---- workspace layout ----
    int* dego      = (int*)d_ws;                   // N
    int* degi      = dego + N;                     // N
    int* excl      = degi + N;                     // N
    int* partials  = excl + N;                     // 256
    int* row_start = partials + 256;               // N+1 (pad to N+64)
    int* cursor    = row_start + N + 64;           // N
    int* eidx      = cursor + N;                   // E
    float* iso     = (float*)(eidx + E);           // N
    float* isi     = iso + N;                      // N
    unsigned short* W1t = (unsigned short*)(isi + N);      // IN_DIM*HID
    unsigned short* W2t = W1t + (size_t)IN_DIM * HID;      // HID*OUTD
    unsigned short* X1b = W2t + (size_t)HID * OUTD;        // N*HID bf16 (67MB)
    unsigned short* X2b = X1b;                             // alias (X1 dead before gemm2 write)
    unsigned short* R2h = X1b + (size_t)N * HID;           // N*HID bf16 (67MB) — x1s

    hipMemsetAsync(dego, 0, sizeof(int) * (size_t)2 * N, stream);

    deg_kernel<<<(E + 255) / 256, 256, 0, stream>>>(src, dst, dego, degi, E);

    // CSR by dst + fused inv-sqrt norms
    scan_block<<<N / 256, 256, 0, stream>>>(degi, excl, partials);
    scan_partials<<<1, 256, 0, stream>>>(partials);
    scan_add_norm<<<N / 256, 256, 0, stream>>>(
        excl, partials, degi, dego, row_start, cursor, iso, isi, N);
    csr_fill<<<(E + 255) / 256, 256, 0, stream>>>(src, dst, cursor, eidx, E);

    // weights -> bf16 transposed (tiled, coalesced)
    {
        dim3 g1(HID / 32, IN_DIM / 32);
        transpose_cvt_tiled<<<g1, 256, 0, stream>>>(W1, W1t, IN_DIM, HID);
        dim3 g2(OUTD / 32, HID / 32);
        transpose_cvt_tiled<<<g2, 256, 0, stream>>>(W2, W2t, HID, OUTD);
    }

    // Layer 1: X1b = bf16(h @ W1) [R16-proven fused f32-A]; aggregate applies iso[src]
    gemm1_f32lds<<<(N / 128) * (HID / 128), 256, 0, stream>>>(h, W1t, X1b, N);
    aggregate<HID, 64, true><<<N / 4, 256, 0, stream>>>(
        row_start, eidx, X1b, isi, iso, b1, R2h, nullptr);

    // Layer 2: X2b = bf16(R2h @ W2) ; out = agg(X2b)*isi + b2  [32 lanes/node]
    gemm2_bf16<<<(N / TM) * (OUTD / TN), 256, 0, stream>>>(
        R2h, W2t, X2b, N, HID, OUTD);
    aggregate<OUTD, 32, false><<<N / 8, 256, 0, stream>>>(
        row_start, eidx, X2b, isi, iso, b2, nullptr, out);
}